// Round 8
// baseline (152.644 us; speedup 1.0000x reference)
//
#include <hip/hip_runtime.h>
#include <stdint.h>

#define B_      32
#define T_      1024
#define D_      512
#define MAXLEN_ 8192

typedef float f4 __attribute__((ext_vector_type(4)));

// ---------------------------------------------------------------------------
// Kernel 1: per-batch shuffle-based inclusive scan (1 barrier) + DIRECT
// scatter of the expansion index: thread t owns output positions
// [cum_prev, cum) and writes t there; tail [mel, 8192) gets -1 (disjoint
// ranges -> no second barrier). mel_len -> tail of d_out.
// ---------------------------------------------------------------------------
__global__ void lr_scan_scatter_kernel(const int* __restrict__ dur,
                                       int* __restrict__ idx,
                                       float* __restrict__ mel_out) {
    int b    = blockIdx.x;
    int t    = threadIdx.x;        // 0..1023
    int lane = t & 63;
    int wave = t >> 6;             // 0..15

    int d = dur[b * T_ + t];

    // wave-level inclusive scan (no barriers)
    int v = d;
    #pragma unroll
    for (int off = 1; off < 64; off <<= 1) {
        int n = __shfl_up(v, off, 64);
        if (lane >= off) v += n;
    }

    __shared__ int wsum[16];
    if (lane == 63) wsum[wave] = v;
    __syncthreads();

    int off = 0, tot = 0;
    #pragma unroll
    for (int w = 0; w < 16; ++w) {
        int s = wsum[w];
        off += (w < wave) ? s : 0;
        tot += s;
    }
    int cum  = v + off;            // inclusive cumsum at position t
    int cump = cum - d;            // exclusive

    if (t == T_ - 1) mel_out[b] = (float)tot;

    int* row = idx + b * MAXLEN_;
    for (int j = cump; j < cum; ++j) row[j] = t;              // d in [0,8)
    for (int p = tot + t; p < MAXLEN_; p += T_) row[p] = -1;  // masked tail
}

// ---------------------------------------------------------------------------
// Kernel 2: persistent-block gather. 2048 blocks (8/CU at 8 VGPR), each
// block owns 128 CONTIGUOUS output rows (16 iterations x 8 rows). Half-wave
// (32 lanes) per row, 4 f4 (64B) per lane; one iteration stores 16KB
// contiguous per block. The next iteration's idx is prefetched before the
// current row's x-load/store, breaking the idx->x dependent chain. Long-
// lived waves amortize launch/drain (the 6.7TB/s harness fills run this
// way at 11% occupancy).
// out[b, p, :] = (idx >= 0) ? x[b, idx, :] : 0
// ---------------------------------------------------------------------------
__global__ __launch_bounds__(256) void lr_gather_kernel(
        const f4* __restrict__ x,
        const int* __restrict__ idx,
        f4* __restrict__ out) {
    int base = (int)blockIdx.x * 128;            // 2048 blocks * 128 rows
    int h    = (int)(threadIdx.x >> 5);          // half-wave id, 0..7
    int c    = (int)(threadIdx.x & 31);          // f4 col base

    int row = base + h;
    int tt  = idx[row];

    #pragma unroll 2
    for (int r = 0; r < 16; ++r) {
        int tn = 0;
        if (r < 15) tn = idx[row + 8];           // prefetch next iteration

        f4* o = out + ((((long long)row) << 7) + c);     // 128 f4 per row
        if (tt >= 0) {
            int b = row >> 13;                           // MAXLEN_ = 2^13
            const f4* src = x + ((((long long)(b * T_ + tt)) << 7) + c);
            o[0]  = src[0];
            o[32] = src[32];
            o[64] = src[64];
            o[96] = src[96];
        } else {
            f4 z = (f4){0.f, 0.f, 0.f, 0.f};
            o[0]  = z;
            o[32] = z;
            o[64] = z;
            o[96] = z;
        }
        row += 8;
        tt = tn;
    }
}

// ---------------------------------------------------------------------------
// Fallback (ws too small for the 1MB idx array): cum in ws + fused search.
// ---------------------------------------------------------------------------
__global__ void lr_cumsum_kernel(const int* __restrict__ dur,
                                 int* __restrict__ cum,
                                 float* __restrict__ mel_out) {
    int b = blockIdx.x;
    int t = threadIdx.x;
    __shared__ int s[T_];
    s[t] = dur[b * T_ + t];
    __syncthreads();
    #pragma unroll
    for (int off = 1; off < T_; off <<= 1) {
        int v = (t >= off) ? s[t - off] : 0;
        __syncthreads();
        s[t] += v;
        __syncthreads();
    }
    cum[b * T_ + t] = s[t];
    if (t == T_ - 1) mel_out[b] = (float)s[t];
}

__global__ void lr_gather_fused_kernel(const f4* __restrict__ x,
                                       const int* __restrict__ cum,
                                       f4* __restrict__ out) {
    const long long total = (long long)B_ * MAXLEN_ * (D_ / 4);
    const long long stride = (long long)gridDim.x * blockDim.x;
    for (long long gid = (long long)blockIdx.x * blockDim.x + threadIdx.x;
         gid < total; gid += stride) {
        int row = (int)(gid >> 7);
        int c   = (int)(gid & 127);
        int b   = row >> 13;
        int p   = row & (MAXLEN_ - 1);
        const int* cm = cum + b * T_;
        int mel = cm[T_ - 1];
        f4 v = (f4){0.f, 0.f, 0.f, 0.f};
        if (p < mel) {
            int lo = 0, hi = T_;
            #pragma unroll
            for (int it = 0; it < 10; ++it) {
                int mid = (lo + hi) >> 1;
                if (cm[mid] <= p) lo = mid + 1; else hi = mid;
            }
            v = x[(((long long)(b * T_ + lo)) << 7) | c];
        }
        out[gid] = v;
    }
}

extern "C" void kernel_launch(void* const* d_in, const int* in_sizes, int n_in,
                              void* d_out, int out_size, void* d_ws, size_t ws_size,
                              hipStream_t stream) {
    const float* x   = (const float*)d_in[0];
    const int*   dur = (const int*)d_in[1];   // harness converts integers to int32
    // d_in[2] = max_len scalar (8192) -- compile-time constant here.

    float* out     = (float*)d_out;
    float* mel_out = out + (size_t)B_ * MAXLEN_ * D_;   // output 1 tail

    const size_t need_idx = (size_t)B_ * MAXLEN_ * sizeof(int);   // 1 MB

    if (ws_size >= need_idx) {
        int* idx = (int*)d_ws;
        lr_scan_scatter_kernel<<<B_, T_, 0, stream>>>(dur, idx, mel_out);
        // 262144 output rows / 128 rows per block = 2048 blocks (8 per CU)
        lr_gather_kernel<<<(B_ * MAXLEN_) / 128, 256, 0, stream>>>(
            (const f4*)x, idx, (f4*)out);
    } else {
        int* cum = (int*)d_ws;                            // 128 KB
        lr_cumsum_kernel<<<B_, T_, 0, stream>>>(dur, cum, mel_out);
        lr_gather_fused_kernel<<<4096, 256, 0, stream>>>((const f4*)x, cum,
                                                         (f4*)out);
    }
}

// Round 9
// 123.506 us; speedup vs baseline: 1.2359x; 1.2359x over previous
//
#include <hip/hip_runtime.h>
#include <stdint.h>

#define B_      32
#define T_      1024
#define D_      512
#define MAXLEN_ 8192

typedef float f4 __attribute__((ext_vector_type(4)));

// ---------------------------------------------------------------------------
// Kernel 1: per-batch shuffle-based inclusive scan (1 barrier) + DIRECT
// scatter of the expansion index: thread t owns output positions
// [cum_prev, cum) and writes t there; tail [mel, 8192) gets -1 (disjoint
// ranges -> no second barrier). mel_len -> tail of d_out.
// ---------------------------------------------------------------------------
__global__ void lr_scan_scatter_kernel(const int* __restrict__ dur,
                                       int* __restrict__ idx,
                                       float* __restrict__ mel_out) {
    int b    = blockIdx.x;
    int t    = threadIdx.x;        // 0..1023
    int lane = t & 63;
    int wave = t >> 6;             // 0..15

    int d = dur[b * T_ + t];

    // wave-level inclusive scan (no barriers)
    int v = d;
    #pragma unroll
    for (int off = 1; off < 64; off <<= 1) {
        int n = __shfl_up(v, off, 64);
        if (lane >= off) v += n;
    }

    __shared__ int wsum[16];
    if (lane == 63) wsum[wave] = v;
    __syncthreads();

    int off = 0, tot = 0;
    #pragma unroll
    for (int w = 0; w < 16; ++w) {
        int s = wsum[w];
        off += (w < wave) ? s : 0;
        tot += s;
    }
    int cum  = v + off;            // inclusive cumsum at position t
    int cump = cum - d;            // exclusive

    if (t == T_ - 1) mel_out[b] = (float)tot;

    int* row = idx + b * MAXLEN_;
    for (int j = cump; j < cum; ++j) row[j] = t;              // d in [0,8)
    for (int p = tot + t; p < MAXLEN_; p += T_) row[p] = -1;  // masked tail
}

// ---------------------------------------------------------------------------
// Kernel 2: gather. 65536 blocks x 256 threads, 4 rows/block, FULL wave per
// row: the mask-vs-gather branch is wave-uniform (no exec divergence; R5's
// half-wave rows mixed two idx values per wave) and idx is one scalar
// broadcast per wave. Lane l owns f4 l and l+64 of its row -> two
// 1KB-contiguous store instructions per row. Block-count is the monotone
// knob on this store stream (4096:135us, 16384:126, 32768:119, 2048
// persistent:153) -- so double it again. XCD-chunked swizzle keeps x-row
// reuse inside one XCD's L2.
// out[b, p, :] = (idx >= 0) ? x[b, idx, :] : 0
// ---------------------------------------------------------------------------
__global__ __launch_bounds__(256) void lr_gather_kernel(
        const f4* __restrict__ x,
        const int* __restrict__ idx,
        f4* __restrict__ out) {
    unsigned bid   = blockIdx.x;
    unsigned chunk = gridDim.x >> 3;                 // 65536/8 = 8192
    unsigned nb    = (bid & 7) * chunk + (bid >> 3); // XCD-chunked swizzle

    int wave = (int)(threadIdx.x >> 6);              // 0..3
    int lane = (int)(threadIdx.x & 63);
    int row  = (int)(nb * 4) + wave;                 // 4 rows/block
    int tt   = idx[row];                             // wave-uniform

    f4* o = out + ((((long long)row) << 7) + lane);  // 128 f4 per row
    if (tt >= 0) {
        int b = row >> 13;                           // MAXLEN_ = 2^13
        const f4* src = x + ((((long long)(b * T_ + tt)) << 7) + lane);
        o[0]  = src[0];
        o[64] = src[64];
    } else {
        f4 z = (f4){0.f, 0.f, 0.f, 0.f};
        o[0]  = z;
        o[64] = z;
    }
}

// ---------------------------------------------------------------------------
// Fallback (ws too small for the 1MB idx array): cum in ws + fused search.
// ---------------------------------------------------------------------------
__global__ void lr_cumsum_kernel(const int* __restrict__ dur,
                                 int* __restrict__ cum,
                                 float* __restrict__ mel_out) {
    int b = blockIdx.x;
    int t = threadIdx.x;
    __shared__ int s[T_];
    s[t] = dur[b * T_ + t];
    __syncthreads();
    #pragma unroll
    for (int off = 1; off < T_; off <<= 1) {
        int v = (t >= off) ? s[t - off] : 0;
        __syncthreads();
        s[t] += v;
        __syncthreads();
    }
    cum[b * T_ + t] = s[t];
    if (t == T_ - 1) mel_out[b] = (float)s[t];
}

__global__ void lr_gather_fused_kernel(const f4* __restrict__ x,
                                       const int* __restrict__ cum,
                                       f4* __restrict__ out) {
    const long long total = (long long)B_ * MAXLEN_ * (D_ / 4);
    const long long stride = (long long)gridDim.x * blockDim.x;
    for (long long gid = (long long)blockIdx.x * blockDim.x + threadIdx.x;
         gid < total; gid += stride) {
        int row = (int)(gid >> 7);
        int c   = (int)(gid & 127);
        int b   = row >> 13;
        int p   = row & (MAXLEN_ - 1);
        const int* cm = cum + b * T_;
        int mel = cm[T_ - 1];
        f4 v = (f4){0.f, 0.f, 0.f, 0.f};
        if (p < mel) {
            int lo = 0, hi = T_;
            #pragma unroll
            for (int it = 0; it < 10; ++it) {
                int mid = (lo + hi) >> 1;
                if (cm[mid] <= p) lo = mid + 1; else hi = mid;
            }
            v = x[(((long long)(b * T_ + lo)) << 7) | c];
        }
        out[gid] = v;
    }
}

extern "C" void kernel_launch(void* const* d_in, const int* in_sizes, int n_in,
                              void* d_out, int out_size, void* d_ws, size_t ws_size,
                              hipStream_t stream) {
    const float* x   = (const float*)d_in[0];
    const int*   dur = (const int*)d_in[1];   // harness converts integers to int32
    // d_in[2] = max_len scalar (8192) -- compile-time constant here.

    float* out     = (float*)d_out;
    float* mel_out = out + (size_t)B_ * MAXLEN_ * D_;   // output 1 tail

    const size_t need_idx = (size_t)B_ * MAXLEN_ * sizeof(int);   // 1 MB

    if (ws_size >= need_idx) {
        int* idx = (int*)d_ws;
        lr_scan_scatter_kernel<<<B_, T_, 0, stream>>>(dur, idx, mel_out);
        // 262144 output rows / 4 rows per block = 65536 blocks (mult of 8)
        lr_gather_kernel<<<(B_ * MAXLEN_) / 4, 256, 0, stream>>>(
            (const f4*)x, idx, (f4*)out);
    } else {
        int* cum = (int*)d_ws;                            // 128 KB
        lr_cumsum_kernel<<<B_, T_, 0, stream>>>(dur, cum, mel_out);
        lr_gather_fused_kernel<<<4096, 256, 0, stream>>>((const f4*)x, cum,
                                                         (f4*)out);
    }
}